// Round 1
// baseline (4666.257 us; speedup 1.0000x reference)
//
#include <hip/hip_runtime.h>

#define EPS 1e-5f
#define NIN 9
#define F1 32
#define F2 64

// ws layout (floats):
// [0,32)   s1      [32,64)  ss1
// [64,128) s2      [128,192) ss2
// [192,224) scale1 [224,256) shift1
// [256,320) scale2 [320,384) shift2

__global__ __launch_bounds__(256) void stats1_kernel(
    const float* __restrict__ pts, const float* __restrict__ w1,
    const float* __restrict__ b1, float* __restrict__ ws, int N)
{
    float s[F1], ss[F1];
#pragma unroll
    for (int j = 0; j < F1; ++j) { s[j] = 0.f; ss[j] = 0.f; }

    const int stride = gridDim.x * blockDim.x;
    for (int i = blockIdx.x * blockDim.x + threadIdx.x; i < N; i += stride) {
        const float* p = pts + (size_t)i * NIN;
        float x[NIN];
#pragma unroll
        for (int k = 0; k < NIN; ++k) x[k] = p[k];
#pragma unroll
        for (int j = 0; j < F1; ++j) {
            float h = b1[j];
#pragma unroll
            for (int k = 0; k < NIN; ++k) h = fmaf(x[k], w1[k * F1 + j], h);
            s[j] += h;
            ss[j] = fmaf(h, h, ss[j]);
        }
    }

    __shared__ float sh[2 * F1];
    if (threadIdx.x < 2 * F1) sh[threadIdx.x] = 0.f;
    __syncthreads();
#pragma unroll
    for (int j = 0; j < F1; ++j) {
        atomicAdd(&sh[j], s[j]);
        atomicAdd(&sh[F1 + j], ss[j]);
    }
    __syncthreads();
    if (threadIdx.x < 2 * F1) atomicAdd(&ws[threadIdx.x], sh[threadIdx.x]);
}

__global__ void finalize_kernel(
    const float* __restrict__ g, const float* __restrict__ be,
    const float* __restrict__ sum_s, const float* __restrict__ sum_ss,
    float* __restrict__ scale, float* __restrict__ shift, int F, float invN)
{
    int j = threadIdx.x;
    if (j < F) {
        float mean = sum_s[j] * invN;
        float var  = sum_ss[j] * invN - mean * mean;
        float rstd = rsqrtf(var + EPS);
        float sc   = g[j] * rstd;
        scale[j] = sc;
        shift[j] = be[j] - mean * sc;
    }
}

__global__ __launch_bounds__(256, 2) void stats2_kernel(
    const float* __restrict__ pts, const float* __restrict__ w1,
    const float* __restrict__ b1, const float* __restrict__ w2,
    const float* __restrict__ b2, float* __restrict__ ws, int N)
{
    const float* sc1 = ws + 192;
    const float* sh1 = ws + 224;

    float s[F2], ss[F2];
#pragma unroll
    for (int j = 0; j < F2; ++j) { s[j] = 0.f; ss[j] = 0.f; }

    const int stride = gridDim.x * blockDim.x;
    for (int i = blockIdx.x * blockDim.x + threadIdx.x; i < N; i += stride) {
        const float* p = pts + (size_t)i * NIN;
        float x[NIN];
#pragma unroll
        for (int k = 0; k < NIN; ++k) x[k] = p[k];

        float f1v[F1];
#pragma unroll
        for (int j = 0; j < F1; ++j) {
            float h = b1[j];
#pragma unroll
            for (int k = 0; k < NIN; ++k) h = fmaf(x[k], w1[k * F1 + j], h);
            f1v[j] = fmaxf(0.f, fmaf(h, sc1[j], sh1[j]));
        }

#pragma unroll
        for (int jc = 0; jc < F2; jc += 16) {
            float h[16];
#pragma unroll
            for (int jj = 0; jj < 16; ++jj) h[jj] = b2[jc + jj];
#pragma unroll
            for (int k = 0; k < F1; ++k) {
                float f = f1v[k];
#pragma unroll
                for (int jj = 0; jj < 16; ++jj)
                    h[jj] = fmaf(f, w2[k * F2 + jc + jj], h[jj]);
            }
#pragma unroll
            for (int jj = 0; jj < 16; ++jj) {
                s[jc + jj] += h[jj];
                ss[jc + jj] = fmaf(h[jj], h[jj], ss[jc + jj]);
            }
        }
    }

    __shared__ float sh[2 * F2];
    if (threadIdx.x < 2 * F2) sh[threadIdx.x] = 0.f;
    __syncthreads();
#pragma unroll
    for (int j = 0; j < F2; ++j) {
        atomicAdd(&sh[j], s[j]);
        atomicAdd(&sh[F2 + j], ss[j]);
    }
    __syncthreads();
    if (threadIdx.x < 2 * F2) atomicAdd(&ws[64 + threadIdx.x], sh[threadIdx.x]);
}

__global__ __launch_bounds__(256, 2) void scatter_kernel(
    const float* __restrict__ pts, const int* __restrict__ idx,
    const float* __restrict__ w1, const float* __restrict__ b1,
    const float* __restrict__ w2, const float* __restrict__ b2,
    const float* __restrict__ ws, unsigned int* __restrict__ out, int N)
{
    const float* sc1 = ws + 192;
    const float* sh1 = ws + 224;
    const float* sc2 = ws + 256;
    const float* sh2 = ws + 320;

    const int stride = gridDim.x * blockDim.x;
    for (int i = blockIdx.x * blockDim.x + threadIdx.x; i < N; i += stride) {
        const float* p = pts + (size_t)i * NIN;
        float x[NIN];
#pragma unroll
        for (int k = 0; k < NIN; ++k) x[k] = p[k];
        int seg = idx[i];
        unsigned int* outp = out + (unsigned int)seg * F2;

        float f1v[F1];
#pragma unroll
        for (int j = 0; j < F1; ++j) {
            float h = b1[j];
#pragma unroll
            for (int k = 0; k < NIN; ++k) h = fmaf(x[k], w1[k * F1 + j], h);
            f1v[j] = fmaxf(0.f, fmaf(h, sc1[j], sh1[j]));
        }

#pragma unroll
        for (int jc = 0; jc < F2; jc += 16) {
            float h[16];
#pragma unroll
            for (int jj = 0; jj < 16; ++jj) h[jj] = b2[jc + jj];
#pragma unroll
            for (int k = 0; k < F1; ++k) {
                float f = f1v[k];
#pragma unroll
                for (int jj = 0; jj < 16; ++jj)
                    h[jj] = fmaf(f, w2[k * F2 + jc + jj], h[jj]);
            }
#pragma unroll
            for (int jj = 0; jj < 16; ++jj) {
                float f2 = fmaf(h[jj], sc2[jc + jj], sh2[jc + jj]);
                // post-ReLU value; out is zero-initialized so f2<=0 contributes nothing.
                if (f2 > 0.f)
                    atomicMax(&outp[jc + jj], __float_as_uint(f2));
            }
        }
    }
}

extern "C" void kernel_launch(void* const* d_in, const int* in_sizes, int n_in,
                              void* d_out, int out_size, void* d_ws, size_t ws_size,
                              hipStream_t stream)
{
    const float* pts = (const float*)d_in[0];
    const int*   idx = (const int*)d_in[1];
    // d_in[2] = num_segments scalar (value known: out_size / F2)
    const float* w1  = (const float*)d_in[3];
    const float* b1  = (const float*)d_in[4];
    const float* g1  = (const float*)d_in[5];
    const float* be1 = (const float*)d_in[6];
    const float* w2  = (const float*)d_in[7];
    const float* b2  = (const float*)d_in[8];
    const float* g2  = (const float*)d_in[9];
    const float* be2 = (const float*)d_in[10];

    float* ws = (float*)d_ws;
    int N = in_sizes[0] / NIN;
    float invN = 1.0f / (float)N;

    hipMemsetAsync(ws, 0, 192 * sizeof(float), stream);
    hipMemsetAsync(d_out, 0, (size_t)out_size * sizeof(float), stream);

    stats1_kernel<<<2048, 256, 0, stream>>>(pts, w1, b1, ws, N);
    finalize_kernel<<<1, 64, 0, stream>>>(g1, be1, ws + 0, ws + 32,
                                          ws + 192, ws + 224, F1, invN);
    stats2_kernel<<<512, 256, 0, stream>>>(pts, w1, b1, w2, b2, ws, N);
    finalize_kernel<<<1, 64, 0, stream>>>(g2, be2, ws + 64, ws + 128,
                                          ws + 256, ws + 320, F2, invN);
    scatter_kernel<<<1024, 256, 0, stream>>>(pts, idx, w1, b1, w2, b2, ws,
                                             (unsigned int*)d_out, N);
}

// Round 2
// 983.982 us; speedup vs baseline: 4.7422x; 4.7422x over previous
//
#include <hip/hip_runtime.h>

#define EPS 1e-5f
#define NIN 9
#define F1 32
#define F2 64
#define TILE 256
#define ROWSTRIDE 36   // floats; 144B row, 16B aligned for float4 LDS ops

// ws layout (floats):
// [0,32)   s1      [32,64)   ss1
// [64,128) s2      [128,192) ss2
// [192,224) scale1 [224,256) shift1
// [256,320) scale2 [320,384) shift2

__device__ __forceinline__ void compute_f1(const float* __restrict__ p,
                                           const float* __restrict__ w1,
                                           const float* __restrict__ b1,
                                           const float* __restrict__ sc1,
                                           const float* __restrict__ sh1,
                                           float* __restrict__ f1v /*[F1]*/)
{
    float x[NIN];
#pragma unroll
    for (int k = 0; k < NIN; ++k) x[k] = p[k];
#pragma unroll
    for (int j = 0; j < F1; ++j) {
        float h = b1[j];
#pragma unroll
        for (int k = 0; k < NIN; ++k) h = fmaf(x[k], w1[k * F1 + j], h);
        f1v[j] = fmaxf(0.f, fmaf(h, sc1[j], sh1[j]));
    }
}

__global__ __launch_bounds__(256) void stats1_kernel(
    const float* __restrict__ pts, const float* __restrict__ w1,
    const float* __restrict__ b1, float* __restrict__ ws, int N)
{
    float s[F1], ss[F1];
#pragma unroll
    for (int j = 0; j < F1; ++j) { s[j] = 0.f; ss[j] = 0.f; }

    const int stride = gridDim.x * blockDim.x;
    for (int i = blockIdx.x * blockDim.x + threadIdx.x; i < N; i += stride) {
        const float* p = pts + (size_t)i * NIN;
        float x[NIN];
#pragma unroll
        for (int k = 0; k < NIN; ++k) x[k] = p[k];
#pragma unroll
        for (int j = 0; j < F1; ++j) {
            float h = b1[j];
#pragma unroll
            for (int k = 0; k < NIN; ++k) h = fmaf(x[k], w1[k * F1 + j], h);
            s[j] += h;
            ss[j] = fmaf(h, h, ss[j]);
        }
    }

    __shared__ float sh[2 * F1];
    if (threadIdx.x < 2 * F1) sh[threadIdx.x] = 0.f;
    __syncthreads();
#pragma unroll
    for (int j = 0; j < F1; ++j) {
        atomicAdd(&sh[j], s[j]);
        atomicAdd(&sh[F1 + j], ss[j]);
    }
    __syncthreads();
    if (threadIdx.x < 2 * F1) atomicAdd(&ws[threadIdx.x], sh[threadIdx.x]);
}

__global__ void finalize_kernel(
    const float* __restrict__ g, const float* __restrict__ be,
    const float* __restrict__ sum_s, const float* __restrict__ sum_ss,
    float* __restrict__ scale, float* __restrict__ shift, int F, float invN)
{
    int j = threadIdx.x;
    if (j < F) {
        float mean = sum_s[j] * invN;
        float var  = sum_ss[j] * invN - mean * mean;
        float rstd = rsqrtf(var + EPS);
        float sc   = g[j] * rstd;
        scale[j] = sc;
        shift[j] = be[j] - mean * sc;
    }
}

// lane = output feature j; wave handles 64 points of a 256-point LDS tile.
__global__ __launch_bounds__(256, 4) void stats2_kernel(
    const float* __restrict__ pts, const float* __restrict__ w1,
    const float* __restrict__ b1, const float* __restrict__ w2,
    const float* __restrict__ b2, float* __restrict__ ws, int N)
{
    __shared__ float f1lds[TILE * ROWSTRIDE];
    __shared__ float rs[F2], rss[F2];

    const float* sc1 = ws + 192;
    const float* sh1 = ws + 224;
    const int lane = threadIdx.x & 63;
    const int wv   = threadIdx.x >> 6;

    float w2col[F1];
#pragma unroll
    for (int k = 0; k < F1; ++k) w2col[k] = w2[k * F2 + lane];
    const float b2j = b2[lane];

    float s = 0.f, ssum = 0.f;
    if (threadIdx.x < F2) { rs[threadIdx.x] = 0.f; rss[threadIdx.x] = 0.f; }

    const int numTiles = (N + TILE - 1) / TILE;
    for (int tile = blockIdx.x; tile < numTiles; tile += gridDim.x) {
        const int base = tile * TILE;
        __syncthreads();   // prior iteration done reading LDS
        {
            const int gi = base + threadIdx.x;
            if (gi < N) {
                float f1v[F1];
                compute_f1(pts + (size_t)gi * NIN, w1, b1, sc1, sh1, f1v);
                float4* wrow = (float4*)&f1lds[threadIdx.x * ROWSTRIDE];
#pragma unroll
                for (int k4 = 0; k4 < 8; ++k4)
                    wrow[k4] = make_float4(f1v[4*k4+0], f1v[4*k4+1],
                                           f1v[4*k4+2], f1v[4*k4+3]);
            }
        }
        __syncthreads();
        const int pbase = wv * 64;
        const int pmax  = min(64, N - base - pbase);
        for (int p = 0; p < pmax; ++p) {
            const float4* row = (const float4*)&f1lds[(pbase + p) * ROWSTRIDE];
            float h = b2j;
#pragma unroll
            for (int k4 = 0; k4 < 8; ++k4) {
                float4 r = row[k4];   // same address for all lanes -> broadcast
                h = fmaf(r.x, w2col[4*k4+0], h);
                h = fmaf(r.y, w2col[4*k4+1], h);
                h = fmaf(r.z, w2col[4*k4+2], h);
                h = fmaf(r.w, w2col[4*k4+3], h);
            }
            s += h;
            ssum = fmaf(h, h, ssum);
        }
    }
    __syncthreads();
    atomicAdd(&rs[lane], s);
    atomicAdd(&rss[lane], ssum);
    __syncthreads();
    if (threadIdx.x < F2) {
        atomicAdd(&ws[64 + threadIdx.x],  rs[threadIdx.x]);
        atomicAdd(&ws[128 + threadIdx.x], rss[threadIdx.x]);
    }
}

__global__ __launch_bounds__(256, 4) void scatter_kernel(
    const float* __restrict__ pts, const int* __restrict__ idx,
    const float* __restrict__ w1, const float* __restrict__ b1,
    const float* __restrict__ w2, const float* __restrict__ b2,
    const float* __restrict__ ws, unsigned int* __restrict__ out, int N)
{
    __shared__ float f1lds[TILE * ROWSTRIDE];
    __shared__ int   seglds[TILE];

    const float* sc1 = ws + 192;
    const float* sh1 = ws + 224;
    const float* sc2 = ws + 256;
    const float* sh2 = ws + 320;
    const int lane = threadIdx.x & 63;
    const int wv   = threadIdx.x >> 6;

    float w2col[F1];
#pragma unroll
    for (int k = 0; k < F1; ++k) w2col[k] = w2[k * F2 + lane];
    const float b2j  = b2[lane];
    const float sc2j = sc2[lane];
    const float sh2j = sh2[lane];

    const int numTiles = (N + TILE - 1) / TILE;
    for (int tile = blockIdx.x; tile < numTiles; tile += gridDim.x) {
        const int base = tile * TILE;
        __syncthreads();
        {
            const int gi = base + threadIdx.x;
            if (gi < N) {
                float f1v[F1];
                compute_f1(pts + (size_t)gi * NIN, w1, b1, sc1, sh1, f1v);
                float4* wrow = (float4*)&f1lds[threadIdx.x * ROWSTRIDE];
#pragma unroll
                for (int k4 = 0; k4 < 8; ++k4)
                    wrow[k4] = make_float4(f1v[4*k4+0], f1v[4*k4+1],
                                           f1v[4*k4+2], f1v[4*k4+3]);
                seglds[threadIdx.x] = idx[gi];
            }
        }
        __syncthreads();
        const int pbase = wv * 64;
        const int pmax  = min(64, N - base - pbase);
        for (int p = 0; p < pmax; ++p) {
            const float4* row = (const float4*)&f1lds[(pbase + p) * ROWSTRIDE];
            float h = b2j;
#pragma unroll
            for (int k4 = 0; k4 < 8; ++k4) {
                float4 r = row[k4];
                h = fmaf(r.x, w2col[4*k4+0], h);
                h = fmaf(r.y, w2col[4*k4+1], h);
                h = fmaf(r.z, w2col[4*k4+2], h);
                h = fmaf(r.w, w2col[4*k4+3], h);
            }
            float f2 = fmaf(h, sc2j, sh2j);
            int   seg = seglds[pbase + p];
            // 64 lanes -> 64 contiguous addresses (4 cache lines), vs 64 lines before
            if (f2 > 0.f)
                atomicMax(out + (size_t)seg * F2 + lane, __float_as_uint(f2));
        }
    }
}

extern "C" void kernel_launch(void* const* d_in, const int* in_sizes, int n_in,
                              void* d_out, int out_size, void* d_ws, size_t ws_size,
                              hipStream_t stream)
{
    const float* pts = (const float*)d_in[0];
    const int*   idx = (const int*)d_in[1];
    const float* w1  = (const float*)d_in[3];
    const float* b1  = (const float*)d_in[4];
    const float* g1  = (const float*)d_in[5];
    const float* be1 = (const float*)d_in[6];
    const float* w2  = (const float*)d_in[7];
    const float* b2  = (const float*)d_in[8];
    const float* g2  = (const float*)d_in[9];
    const float* be2 = (const float*)d_in[10];

    float* ws = (float*)d_ws;
    int N = in_sizes[0] / NIN;
    float invN = 1.0f / (float)N;

    hipMemsetAsync(ws, 0, 192 * sizeof(float), stream);
    hipMemsetAsync(d_out, 0, (size_t)out_size * sizeof(float), stream);

    stats1_kernel<<<2048, 256, 0, stream>>>(pts, w1, b1, ws, N);
    finalize_kernel<<<1, 64, 0, stream>>>(g1, be1, ws + 0, ws + 32,
                                          ws + 192, ws + 224, F1, invN);
    stats2_kernel<<<2048, 256, 0, stream>>>(pts, w1, b1, w2, b2, ws, N);
    finalize_kernel<<<1, 64, 0, stream>>>(g2, be2, ws + 64, ws + 128,
                                          ws + 256, ws + 320, F2, invN);
    scatter_kernel<<<2048, 256, 0, stream>>>(pts, idx, w1, b1, w2, b2, ws,
                                             (unsigned int*)d_out, N);
}